// Round 9
// baseline (225.563 us; speedup 1.0000x reference)
//
#include <hip/hip_runtime.h>

// Problem dims (fixed by reference setup_inputs)
#define BB 16
#define HH 512
#define WW 512
#define HWSZ (HH * WW)
#define NPIX ((double)(BB * HH * WW))
#define NBLOCKS 4096   // 4096 blocks * 256 thr = 2^20 threads = 1 quad (4 px) each

#define L2E 1.4426950408889634f   // log2(e)
#define LN2 0.6931471805599453    // ln(2)

// hardware transcendentals: v_exp_f32 = 2^x, v_log_f32 = log2(x)
__device__ __forceinline__ float hw_exp2(float x) { return __builtin_amdgcn_exp2f(x); }
__device__ __forceinline__ float hw_log2(float x) { return __builtin_amdgcn_logf(x); }

// DIRS as (dx, dy): shifted[i][h][w] = c_map[h - dy_i][w - dx_i] (zero fill)
// [(1,1),(0,1),(-1,1),(1,0),(-1,0),(1,-1),(0,-1),(-1,-1)]

// 1 quad/thread keeps per-thread state ~75 data VGPRs + working < 128, so the
// (256,4) budget holds WITHOUT scratch spills (R6/R7 theory: 2-quad state
// ~160 regs > 128 -> window arrays spilled -> flat ~77us floor).
__global__ __launch_bounds__(256, 4) void bicon_main(
    const float* __restrict__ cmap,   // [B,2,H,W]
    const int*   __restrict__ target, // [B,H,W]
    const float* __restrict__ con,    // [B,8,H,W]
    double* __restrict__ partials)    // [gridDim.x]
{
    constexpr int dxs[8] = {1, 0, -1, 1, -1, 1, 0, -1};
    constexpr int dys[8] = {1, 1,  1, 0,  0, -1, -1, -1};

    const int tid = blockIdx.x * blockDim.x + threadIdx.x;
    // 2^20 threads: w4idx 7b | h 9b | b 4b
    const int w4 = (tid & 127) * 4;
    const int h  = (tid >> 7) & 511;
    const int b  = tid >> 16;

    const float* __restrict__ c0p = cmap + (size_t)(b * 2) * HWSZ;
    const float* __restrict__ c1p = c0p + HWSZ;
    const size_t roff = (size_t)h * WW + w4;

    const bool upok = (h > 0);
    const bool dnok = (h < HH - 1);
    const bool lok  = (w4 > 0);
    const bool rok  = (w4 < WW - 4);

    // ---- issue all vector loads up front (15 VMEM), named values ----
    const float4 C0 = *(const float4*)(c0p + roff);
    const float4 C1 = *(const float4*)(c1p + roff);
    const int4   TG = *(const int4*)(target + (size_t)b * HWSZ + roff);

    float4 U0 = {0,0,0,0}, U1 = {0,0,0,0}, D0 = {0,0,0,0}, D1 = {0,0,0,0};
    if (upok) { U0 = *(const float4*)(c0p + roff - WW); U1 = *(const float4*)(c1p + roff - WW); }
    if (dnok) { D0 = *(const float4*)(c0p + roff + WW); D1 = *(const float4*)(c1p + roff + WW); }

    const float* cb = con + (size_t)(b * 8) * HWSZ + roff;
    float4 CV[8];
    #pragma unroll
    for (int i = 0; i < 8; ++i)
        CV[i] = *(const float4*)(cb + (size_t)i * HWSZ);

    // ---- guarded halo scalars (12, L1-resident) ----
    const float u0l = (upok && lok) ? c0p[roff - WW - 1] : 0.0f;
    const float u0r = (upok && rok) ? c0p[roff - WW + 4] : 0.0f;
    const float u1l = (upok && lok) ? c1p[roff - WW - 1] : 0.0f;
    const float u1r = (upok && rok) ? c1p[roff - WW + 4] : 0.0f;
    const float m0l = lok ? c0p[roff - 1] : 0.0f;
    const float m0r = rok ? c0p[roff + 4] : 0.0f;
    const float m1l = lok ? c1p[roff - 1] : 0.0f;
    const float m1r = rok ? c1p[roff + 4] : 0.0f;
    const float d0l = (dnok && lok) ? c0p[roff + WW - 1] : 0.0f;
    const float d0r = (dnok && rok) ? c0p[roff + WW + 4] : 0.0f;
    const float d1l = (dnok && lok) ? c1p[roff + WW - 1] : 0.0f;
    const float d1r = (dnok && rok) ? c1p[roff + WW + 4] : 0.0f;

    // Window rows h-1,h,h+1 (r=0..2), cols w4-1..w4+4 (c=0..5); all indices
    // below are compile-time after unrolling -> SROA keeps these in VGPRs.
    const float n0[3][6] = {{u0l, U0.x, U0.y, U0.z, U0.w, u0r},
                            {m0l, C0.x, C0.y, C0.z, C0.w, m0r},
                            {d0l, D0.x, D0.y, D0.z, D0.w, d0r}};
    const float n1[3][6] = {{u1l, U1.x, U1.y, U1.z, U1.w, u1r},
                            {m1l, C1.x, C1.y, C1.z, C1.w, m1r},
                            {d1l, D1.x, D1.y, D1.z, D1.w, d1r}};

    const float cc0[4] = {C0.x, C0.y, C0.z, C0.w};
    const float cc1[4] = {C1.x, C1.y, C1.z, C1.w};
    const int   tt[4]  = {TG.x, TG.y, TG.z, TG.w};

    // accumulators: softplus terms kept in log2 units (ln2 applied at end)
    float acc_min_l2 = 0.0f;
    float acc_ce_l2  = 0.0f;
    float acc_ce_lin = 0.0f;

    // ---- CE (C=2): lse - c_t = max(0, c_other - c_t) + softplus(-|c0-c1|)
    #pragma unroll
    for (int j = 0; j < 4; ++j) {
        const float dl = cc0[j] - cc1[j];
        acc_ce_l2 += hw_log2(1.0f + hw_exp2(-fabsf(dl) * L2E));
        const float lin = (tt[j] == 0) ? -dl : dl;
        acc_ce_lin += fmaxf(lin, 0.0f);
    }

    // ---- 8-dir edge/min-prob: min_c softmax = sigmoid(-|d|);
    //      -log1p(-that) = softplus(-|d|).  edge == con value (con in {0,1}).
    #pragma unroll
    for (int i = 0; i < 8; ++i) {
        const int rr = 1 - dys[i];                // neighbor window row
        const float cts[4] = {CV[i].x, CV[i].y, CV[i].z, CV[i].w};
        #pragma unroll
        for (int j = 0; j < 4; ++j) {
            const int cidx = j - dxs[i] + 1;      // neighbor window col
            const float d = fmaf(cc0[j], n0[rr][cidx], -(cc1[j] * n1[rr][cidx]));
            const float term = hw_log2(1.0f + hw_exp2(-fabsf(d) * L2E));
            acc_min_l2 = fmaf(term, cts[j], acc_min_l2);  // edge mask as multiply
        }
    }

    // combine with final weights: 0.8*mean_ce + 0.2*mean_min (ln2 applied here)
    double contrib = (0.8 / NPIX) * ((double)acc_ce_lin + LN2 * (double)acc_ce_l2)
                   + (0.2 * LN2 / (8.0 * NPIX)) * (double)acc_min_l2;

    // block reduce (wave64 shuffle, then LDS across 4 waves)
    #pragma unroll
    for (int off = 32; off > 0; off >>= 1)
        contrib += __shfl_down(contrib, off);

    __shared__ double sm[4];
    const int lane = threadIdx.x & 63;
    const int wid  = threadIdx.x >> 6;
    if (lane == 0) sm[wid] = contrib;
    __syncthreads();
    if (threadIdx.x == 0)
        partials[blockIdx.x] = sm[0] + sm[1] + sm[2] + sm[3];
}

__global__ __launch_bounds__(256) void bicon_finalize(
    const double* __restrict__ partials, int n, float* __restrict__ out)
{
    double s = 0.0;
    for (int i = threadIdx.x; i < n; i += blockDim.x) s += partials[i];
    #pragma unroll
    for (int off = 32; off > 0; off >>= 1)
        s += __shfl_down(s, off);

    __shared__ double sm[4];
    const int lane = threadIdx.x & 63;
    const int wid  = threadIdx.x >> 6;
    if (lane == 0) sm[wid] = s;
    __syncthreads();
    if (threadIdx.x == 0)
        out[0] = (float)(sm[0] + sm[1] + sm[2] + sm[3]);
}

extern "C" void kernel_launch(void* const* d_in, const int* in_sizes, int n_in,
                              void* d_out, int out_size, void* d_ws, size_t ws_size,
                              hipStream_t stream) {
    const float* cmap   = (const float*)d_in[0];
    const int*   target = (const int*)d_in[1];
    const float* con    = (const float*)d_in[2];
    float* out = (float*)d_out;
    double* partials = (double*)d_ws;

    bicon_main<<<NBLOCKS, 256, 0, stream>>>(cmap, target, con, partials);
    bicon_finalize<<<1, 256, 0, stream>>>(partials, NBLOCKS, out);
}